// Round 1
// baseline (1029.318 us; speedup 1.0000x reference)
//
#include <hip/hip_runtime.h>
#include <math.h>

#define NBROWS 262144

// d_ws layout (floats):
// [0,1024)      S1_ss   : c0*(w1_ss[uvw]+w1_ss[vuw]) for u<v, c0*w for u==v  (M=8,W=16)
// [1024,2048)   S1_vv0  : same with c0/sqrt(3)
// [2048,3072)   C1_sv   : c1/sqrt(3)*(w1_sv[uvw]+w1_vs[vuw])
// [3072,4096)   A1_vv1  : c1/sqrt(6)*(w1_vv1[uvw]-w1_vv1[vuw]) for u<v
// [4096,6144)   S2_ss   (M=16,W=8)
// [6144,8192)   S2_vv0
// [8192,10240)  C2_sv
// [10240,12288) A2_vv1

__global__ __launch_bounds__(256) void prep_kernel(
    const float* __restrict__ w1_ss, const float* __restrict__ w1_vv0,
    const float* __restrict__ w1_sv, const float* __restrict__ w1_vs,
    const float* __restrict__ w1_vv1,
    const float* __restrict__ w2_ss, const float* __restrict__ w2_vv0,
    const float* __restrict__ w2_sv, const float* __restrict__ w2_vs,
    const float* __restrict__ w2_vv1,
    float* __restrict__ ws)
{
    const float inv3 = 0.5773502691896258f;
    const float inv6 = 0.4082482904638631f;
    int i = blockIdx.x * 256 + threadIdx.x;
    if (i >= 12288) return;
    float val = 0.f;
    if (i < 4096) {
        const float c0 = 0.08838834764831845f;   // 1/sqrt(8*8+8*8)
        const float c1 = 0.125f;                  // sqrt(3/(2*64+64))
        int a = i >> 10, r = i & 1023;
        int w = r & 15, uv = r >> 4, u = uv >> 3, vq = uv & 7;
        int tr = (vq * 8 + u) * 16 + w;           // transposed (v,u) index
        if (a == 0)      val = (u < vq) ? c0 * (w1_ss[r] + w1_ss[tr]) : ((u == vq) ? c0 * w1_ss[r] : 0.f);
        else if (a == 1) { const float cc = c0 * inv3;
                           val = (u < vq) ? cc * (w1_vv0[r] + w1_vv0[tr]) : ((u == vq) ? cc * w1_vv0[r] : 0.f); }
        else if (a == 2) val = (c1 * inv3) * (w1_sv[r] + w1_vs[tr]);
        else             val = (u < vq) ? (c1 * inv6) * (w1_vv1[r] - w1_vv1[tr]) : 0.f;
    } else {
        const float c0 = 0.04419417382415922f;   // 1/sqrt(16*16+16*16)
        const float c1 = 0.0625f;                 // sqrt(3/(2*256+256))
        int j = i - 4096;
        int a = j >> 11, r = j & 2047;
        int w = r & 7, uv = r >> 3, u = uv >> 4, vq = uv & 15;
        int tr = (vq * 16 + u) * 8 + w;
        if (a == 0)      val = (u < vq) ? c0 * (w2_ss[r] + w2_ss[tr]) : ((u == vq) ? c0 * w2_ss[r] : 0.f);
        else if (a == 1) { const float cc = c0 * inv3;
                           val = (u < vq) ? cc * (w2_vv0[r] + w2_vv0[tr]) : ((u == vq) ? cc * w2_vv0[r] : 0.f); }
        else if (a == 2) val = (c1 * inv3) * (w2_sv[r] + w2_vs[tr]);
        else             val = (u < vq) ? (c1 * inv6) * (w2_vv1[r] - w2_vv1[tr]) : 0.f;
    }
    ws[i] = val;
}

template<int M, int W>
__device__ __forceinline__ void fctp_folded(
    const float* __restrict__ Sss, const float* __restrict__ Svv0,
    const float* __restrict__ Csv, const float* __restrict__ Avv1,
    const float (&s)[M], const float (&v)[M][3],
    float (&os)[W], float (&ov)[W][3])
{
#pragma unroll
    for (int w = 0; w < W; ++w) { os[w] = 0.f; ov[w][0] = 0.f; ov[w][1] = 0.f; ov[w][2] = 0.f; }
    // scalar output: paths ss + vv0 (symmetric features -> triangular loop, symmetrized weights)
#pragma unroll
    for (int u = 0; u < M; ++u) {
#pragma unroll
        for (int vv = u; vv < M; ++vv) {
            float p = s[u] * s[vv];
            float d = v[u][0]*v[vv][0] + v[u][1]*v[vv][1] + v[u][2]*v[vv][2];
            const float* pss = Sss  + (u*M+vv)*W;
            const float* pvv = Svv0 + (u*M+vv)*W;
#pragma unroll
            for (int w = 0; w < W; ++w) os[w] += p * pss[w] + d * pvv[w];
        }
    }
    // vector output: combined sv+vs path  (t[v,w] = sum_u s[u]*Wc[u,v,w])
#pragma unroll
    for (int vv = 0; vv < M; ++vv) {
#pragma unroll
        for (int w = 0; w < W; ++w) {
            float t = 0.f;
#pragma unroll
            for (int u = 0; u < M; ++u) t += s[u] * Csv[(u*M+vv)*W + w];
            ov[w][0] += t * v[vv][0];
            ov[w][1] += t * v[vv][1];
            ov[w][2] += t * v[vv][2];
        }
    }
    // vector output: vv1 path (cross product, antisymmetric -> u<v pairs, antisymmetrized weights)
#pragma unroll
    for (int u = 0; u < M; ++u) {
#pragma unroll
        for (int vv = u + 1; vv < M; ++vv) {
            float cx = v[u][1]*v[vv][2] - v[u][2]*v[vv][1];
            float cy = v[u][2]*v[vv][0] - v[u][0]*v[vv][2];
            float cz = v[u][0]*v[vv][1] - v[u][1]*v[vv][0];
            const float* pa = Avv1 + (u*M+vv)*W;
#pragma unroll
            for (int w = 0; w < W; ++w) {
                float t = pa[w];
                ov[w][0] += t * cx;
                ov[w][1] += t * cy;
                ov[w][2] += t * cz;
            }
        }
    }
}

template<int N>
__device__ __forceinline__ void si_norm_dev(float (&ys)[N], float (&yv)[N][3])
{
    float sum = 0.f;
#pragma unroll
    for (int i = 0; i < N; ++i) sum += ys[i];
    float m = sum * (1.f / N);
    float var = 0.f;
#pragma unroll
    for (int i = 0; i < N; ++i) { float dd = ys[i] - m; var += dd * dd; }
    float stds = sqrtf(var * (1.f / (N - 1)));
    float invs = 1.f / (stds + 1e-9f);
#pragma unroll
    for (int i = 0; i < N; ++i) ys[i] *= invs;

    float n1[N];
    float sumn = 0.f;
#pragma unroll
    for (int i = 0; i < N; ++i) {
        n1[i] = sqrtf(yv[i][0]*yv[i][0] + yv[i][1]*yv[i][1] + yv[i][2]*yv[i][2] + 1e-9f);
        sumn += n1[i];
    }
    float mn = sumn * (1.f / N);
    float varn = 0.f;
#pragma unroll
    for (int i = 0; i < N; ++i) { float dd = n1[i] - mn; varn += dd * dd; }
    float stdv = sqrtf(varn * (1.f / (N - 1)));
    float invv = 1.f / (stdv + 1e-9f);
#pragma unroll
    for (int i = 0; i < N; ++i) { yv[i][0] *= invv; yv[i][1] *= invv; yv[i][2] *= invv; }
}

template<int N>
__device__ __forceinline__ void tv_norm_dev(float (&xs)[N], float (&xv)[N][3])
{
    float ss = 0.f;
#pragma unroll
    for (int i = 0; i < N; ++i) ss += xs[i]*xs[i];
    float invs = 1.f / sqrtf(ss + 1e-6f);
#pragma unroll
    for (int i = 0; i < N; ++i) xs[i] *= invs;
    float a0 = 0.f, a1 = 0.f, a2 = 0.f;
#pragma unroll
    for (int i = 0; i < N; ++i) { a0 += xv[i][0]*xv[i][0]; a1 += xv[i][1]*xv[i][1]; a2 += xv[i][2]*xv[i][2]; }
    float nm = (sqrtf(a0 + 1e-6f) + sqrtf(a1 + 1e-6f) + sqrtf(a2 + 1e-6f)) * (1.f / 3.f);
    float invv = 1.f / (nm + 1e-6f);
#pragma unroll
    for (int i = 0; i < N; ++i) { xv[i][0] *= invv; xv[i][1] *= invv; xv[i][2] *= invv; }
}

__global__ __launch_bounds__(256) void DoubleLayer_main_kernel(
    const float* __restrict__ x,
    const float* __restrict__ ws,
    float* __restrict__ out)
{
    int row = blockIdx.x * 256 + threadIdx.x;
    const float* xr = x + (size_t)row * 32;

    float xraw[32];
#pragma unroll
    for (int i = 0; i < 8; ++i) {
        float4 t = reinterpret_cast<const float4*>(xr)[i];
        xraw[4*i+0] = t.x; xraw[4*i+1] = t.y; xraw[4*i+2] = t.z; xraw[4*i+3] = t.w;
    }

    float s1[8], v1[8][3];
#pragma unroll
    for (int u = 0; u < 8; ++u) s1[u] = tanhf(xraw[u]);
#pragma unroll
    for (int u = 0; u < 8; ++u) {
        v1[u][0] = xraw[8 + 3*u + 0];
        v1[u][1] = xraw[8 + 3*u + 1];
        v1[u][2] = xraw[8 + 3*u + 2];
    }

    float ys[16], yv[16][3];
    fctp_folded<8,16>(ws + 0, ws + 1024, ws + 2048, ws + 3072, s1, v1, ys, yv);
    si_norm_dev<16>(ys, yv);
    tv_norm_dev<16>(ys, yv);

    float zs[8], zv[8][3];
    fctp_folded<16,8>(ws + 4096, ws + 6144, ws + 8192, ws + 10240, ys, yv, zs, zv);
    si_norm_dev<8>(zs, zv);

    float o[32];
#pragma unroll
    for (int w = 0; w < 8; ++w) o[w] = 1.f / (1.f + expf(-zs[w]));
#pragma unroll
    for (int w = 0; w < 8; ++w) {
        o[8 + 3*w + 0] = zv[w][0];
        o[8 + 3*w + 1] = zv[w][1];
        o[8 + 3*w + 2] = zv[w][2];
    }
    float4* orow = reinterpret_cast<float4*>(out + (size_t)row * 32);
#pragma unroll
    for (int i = 0; i < 8; ++i) orow[i] = make_float4(o[4*i+0], o[4*i+1], o[4*i+2], o[4*i+3]);
}

extern "C" void kernel_launch(void* const* d_in, const int* in_sizes, int n_in,
                              void* d_out, int out_size, void* d_ws, size_t ws_size,
                              hipStream_t stream)
{
    const float* x = (const float*)d_in[0];
    float* ws = (float*)d_ws;
    prep_kernel<<<48, 256, 0, stream>>>(
        (const float*)d_in[1], (const float*)d_in[2], (const float*)d_in[3],
        (const float*)d_in[4], (const float*)d_in[5],
        (const float*)d_in[6], (const float*)d_in[7], (const float*)d_in[8],
        (const float*)d_in[9], (const float*)d_in[10], ws);
    DoubleLayer_main_kernel<<<NBROWS/256, 256, 0, stream>>>(x, ws, (float*)d_out);
}